// Round 11
// baseline (2398.737 us; speedup 1.0000x reference)
//
#include <hip/hip_runtime.h>
#include <math.h>

#define NTOK 16384
#define KD   2048
#define NE   256
#define NCHUNK 64             // K step 32
#define CHUNK_DW 4096         // NE*16 dwords per 16-K chunk image
#define TM 32                 // tokens per block
#define SL 257                // Ls row stride (floats)
#define SA 260                // As2 row stride (floats)

typedef float f32x2 __attribute__((ext_vector_type(2)));

// ---- kernel 0: pre-transform W into chunked, lane-linear slab image (as r6).
// Slab s = (e>>5)*2 + ((e>>4)&1), slot lane = (e&15)*4 + l.
// Bt[c][s*256 + lane*4 + q] = W[e][16c + 4q + l]
__global__ __launch_bounds__(256) void transform_kernel(
    const float* __restrict__ wgt, float* __restrict__ Bt)
{
    const int c    = blockIdx.x >> 2;
    const int qt   = blockIdx.x & 3;
    const int slot = qt * 256 + threadIdx.x;      // 0..1023
    const int s    = slot >> 6;                   // slab 0..15
    const int lane = slot & 63;
    const int em   = lane >> 2;
    const int l    = lane & 3;
    const int e    = (s >> 1) * 32 + (s & 1) * 16 + em;
    const float* src = wgt + (size_t)e * KD + 16 * c + l;
    float4 v = make_float4(src[0], src[4], src[8], src[12]);   // q = 0..3
    *(float4*)(Bt + (size_t)c * CHUNK_DW + slot * 4) = v;
}

typedef __attribute__((address_space(1))) const void GV;
typedef __attribute__((address_space(3))) void LV;
__device__ __forceinline__ void gld_lds16(const float* g, float* l) {
    __builtin_amdgcn_global_load_lds((GV*)g, (LV*)l, 16, 0, 0);
}

// Bit-exact numpy npyv(SSE3,no-FMA) einsum; lane-chains split across thread
// quads (l=tid&3); token-pairs as native f32x2 vector math (componentwise
// IEEE), FMA contraction disabled -> same op DAG as the reference.
__global__ __launch_bounds__(512, 4) void gate_kernel(
    const float* __restrict__ hid, const float* __restrict__ Bt,
    float* __restrict__ out, float* __restrict__ cnt, float* __restrict__ prb)
{
#pragma clang fp contract(off)
    __shared__ union { float bs[2][2 * CHUNK_DW]; float ls[TM][SL]; } sh;
    __shared__ float As2[2][4][SA];   // [buf][l][pair*16 + q*2 + par]
    __shared__ float maxS[TM], sumS[TM], invS[TM];

    const int tid  = threadIdx.x;
    const int lane = tid & 63;
    const int w    = tid >> 6;
    const int l    = tid & 3;
    const int eg   = (tid >> 2) & 31;
    const int tg   = tid >> 7;             // token group 0..3 (8 tokens each)
    const int h    = w & 1;                // expert half within slab pair
    const int t0   = blockIdx.x * TM;

    f32x2 acc2[4][8];                      // [token-pair][j]
#pragma unroll
    for (int i = 0; i < 4; ++i)
#pragma unroll
        for (int j = 0; j < 8; ++j) acc2[i][j] = (f32x2){0.f, 0.f};

    // ---- A staging: 32 lanes/wave (4 tokens x 8 q-octets), float4 = l 0..3 ----
    const bool aact = (lane < 32);
    const int  at   = w * 4 + (lane >> 3);   // token 0..31
    const int  aq   = lane & 7;              // q 0..7
    float av[4];

    auto stageA_load = [&](int c) {          // c in BK=32 units
        if (aact)
            *(float4*)av = *(const float4*)(hid + (size_t)(t0 + at) * KD + 32 * c + 4 * aq);
    };
    auto stageA_write = [&](int buf) {
        if (aact) {
            const int base = (at >> 1) * 16 + aq * 2 + (at & 1);
#pragma unroll
            for (int ll = 0; ll < 4; ++ll)
                As2[buf][ll][base] = av[ll];
        }
    };
    auto stageB = [&](int c, int buf) {      // two 16-chunks per BK=32 step
        const float* src = Bt + (size_t)(2 * c) * CHUNK_DW + tid * 4;
        float* dst = &sh.bs[buf][tid * 4];
#pragma unroll
        for (int s = 0; s < 4; ++s)
            gld_lds16(src + s * 2048, dst + s * 2048);
    };

    stageA_load(0);
    stageB(0, 0);
    stageA_write(0);
    int cur = 0;

#pragma unroll 1
    for (int c = 0; c < NCHUNK; ++c) {
        __syncthreads();                       // cur buffers ready; nxt free
        const int nxt = cur ^ 1;
        if (c + 1 < NCHUNK) { stageA_load(c + 1); stageB(c + 1, nxt); }

#pragma unroll
        for (int j16 = 0; j16 < 2; ++j16) {    // 16-blocks in ascending k
            f32x2 aQ[4][4];                    // [tp][q]
#pragma unroll
            for (int tp = 0; tp < 4; ++tp) {
                const f32x2* ap = (const f32x2*)&As2[cur][l][(tg * 4 + tp) * 16 + j16 * 8];
                aQ[tp][0] = ap[0];             // {tok-even, tok-odd} at q=0
                aQ[tp][1] = ap[1];
                aQ[tp][2] = ap[2];
                aQ[tp][3] = ap[3];
            }
#pragma unroll
            for (int j = 0; j < 8; ++j) {
                const float4 b = *(const float4*)
                    &sh.bs[cur][j16 * CHUNK_DW + ((j * 2 + h) << 8) + (lane << 2)];
#pragma unroll
                for (int tp = 0; tp < 4; ++tp) {
                    f32x2 s = acc2[tp][j];
                    s = aQ[tp][3] * b.w + s;   // q=3: round(mul), round(add)
                    s = aQ[tp][2] * b.z + s;   // q=2
                    s = aQ[tp][1] * b.y + s;   // q=1
                    s = aQ[tp][0] * b.x + s;   // q=0
                    acc2[tp][j] = s;
                }
            }
        }
        if (c + 1 < NCHUNK) stageA_write(nxt);
        cur = nxt;
    }

    // ---- combine lane-chains: (s0+s1)+(s2+s3) per component ----
    __syncthreads();                       // all waves done with sh.bs
#pragma unroll
    for (int tp = 0; tp < 4; ++tp)
#pragma unroll
        for (int j = 0; j < 8; ++j) {
            float sx = acc2[tp][j].x, sy = acc2[tp][j].y;
            sx = __fadd_rn(sx, __shfl_xor(sx, 1));
            sx = __fadd_rn(sx, __shfl_xor(sx, 2));
            sy = __fadd_rn(sy, __shfl_xor(sy, 1));
            sy = __fadd_rn(sy, __shfl_xor(sy, 2));
            if (l == 0) {
                sh.ls[tg * 8 + 2 * tp][eg + 32 * j]     = sx;
                sh.ls[tg * 8 + 2 * tp + 1][eg + 32 * j] = sy;
            }
        }
    if (tid < TM) sumS[tid] = 0.f;
    __syncthreads();

    // ---- per-token top-k (threads 0..31), fp32 bit-exact ----
    if (tid < TM) {
        const float* lr = &sh.ls[tid][0];
        float tv[8]; int ti[8];
#pragma unroll
        for (int j = 0; j < 8; ++j) { tv[j] = -1e30f; ti[j] = 0; }
        float rowmax = -1e30f;

        auto ins8 = [&](float v, int idx) {
#pragma unroll
            for (int p = 0; p < 8; ++p) {
                if (v > tv[p]) {
#pragma unroll
                    for (int q = 7; q > p; --q) { tv[q] = tv[q - 1]; ti[q] = ti[q - 1]; }
                    tv[p] = v; ti[p] = idx;
                    break;
                }
            }
        };

#pragma unroll 1
        for (int g = 0; g < 8; ++g) {
            float v0 = -1e30f, v1 = -1e30f, v2 = -1e30f, v3 = -1e30f;
            int   i0 = 0, i1 = 0, i2 = 0, i3 = 0;
            for (int j = 0; j < 32; ++j) {
                const float v = lr[g * 32 + j];
                if (v > v0)      { v3=v2;i3=i2; v2=v1;i2=i1; v1=v0;i1=i0; v0=v;i0=j; }
                else if (v > v1) { v3=v2;i3=i2; v2=v1;i2=i1; v1=v;i1=j; }
                else if (v > v2) { v3=v2;i3=i2; v2=v;i2=j; }
                else if (v > v3) { v3=v;i3=j; }
            }
            rowmax = fmaxf(rowmax, v0);
            ins8(v0, g * 32 + i0);
            ins8(v1, g * 32 + i1);
            ins8(v2, g * 32 + i2);
            ins8(v3, g * 32 + i3);
        }

        const float s01 = __fadd_rn(tv[0], tv[1]);
        const float s23 = __fadd_rn(tv[2], tv[3]);
        const float s45 = __fadd_rn(tv[4], tv[5]);
        const float s67 = __fadd_rn(tv[6], tv[7]);
        float s = __fadd_rn(__fadd_rn(s01, s23), __fadd_rn(s45, s67));
        s = __fadd_rn(s, 1e-20f);

        const size_t tg2 = (size_t)(t0 + tid);
#pragma unroll
        for (int j = 0; j < 8; ++j) {
            out[tg2 * 8 + j]                    = (float)ti[j];
            out[(size_t)NTOK * 8 + tg2 * 8 + j] = __fdiv_rn(tv[j], s);
            atomicAdd(&cnt[ti[j]], 1.0f);
        }
        maxS[tid] = rowmax;
    }
    __syncthreads();

    // ---- per-token softmax denominator (16 threads per token) ----
    {
        const int t  = tid >> 4;
        const int c0 = (tid & 15) * 16;
        const float m = maxS[t];
        float part = 0.f;
#pragma unroll
        for (int j = 0; j < 16; ++j) part += __expf(sh.ls[t][c0 + j] - m);
        atomicAdd(&sumS[t], part);
    }
    __syncthreads();
    if (tid < TM) invS[tid] = 1.0f / sumS[tid];
    __syncthreads();

    // ---- per-expert softmax-prob partial over block tokens ----
    if (tid < NE) {
        float p = 0.f;
#pragma unroll
        for (int n = 0; n < TM; ++n) p += __expf(sh.ls[n][tid] - maxS[n]) * invS[n];
        atomicAdd(&prb[tid], p);
    }
}

__global__ void aux_kernel(const float* __restrict__ cnt,
                           const float* __restrict__ prb,
                           float* __restrict__ out)
{
    const int tid = threadIdx.x;
    float v = cnt[tid] * prb[tid];
#pragma unroll
    for (int off = 32; off; off >>= 1) v += __shfl_down(v, off, 64);
    __shared__ float ps[4];
    if ((tid & 63) == 0) ps[tid >> 6] = v;
    __syncthreads();
    if (tid == 0) {
        const float tot = ps[0] + ps[1] + ps[2] + ps[3];
        out[(size_t)NTOK * 8 * 2] = tot * (0.001f / (131072.0f * 16384.0f));
    }
}

extern "C" void kernel_launch(void* const* d_in, const int* in_sizes, int n_in,
                              void* d_out, int out_size, void* d_ws, size_t ws_size,
                              hipStream_t stream)
{
    (void)in_sizes; (void)n_in; (void)out_size; (void)ws_size;
    const float* hid = (const float*)d_in[0];
    const float* wgt = (const float*)d_in[1];
    float* out = (float*)d_out;
    float* cnt = (float*)d_ws;             // 256 f
    float* prb = cnt + NE;                 // 256 f
    float* Bt  = prb + NE;                 // 2 MB image (16B-aligned offset)

    hipMemsetAsync(d_ws, 0, 2 * NE * sizeof(float), stream);
    transform_kernel<<<512, 256, 0, stream>>>(wgt, Bt);
    gate_kernel<<<NTOK / TM, 512, 0, stream>>>(hid, Bt, out, cnt, prb);
    aux_kernel<<<1, 256, 0, stream>>>(cnt, prb, out);
}

// Round 12
// 759.672 us; speedup vs baseline: 3.1576x; 3.1576x over previous
//
#include <hip/hip_runtime.h>
#include <math.h>

#define NTOK 16384
#define KD   2048
#define NE   256
#define NCHUNK 64             // K step 32
#define CHUNK_DW 4096         // NE*16 dwords per 16-K chunk image
#define TM 32                 // tokens per block
#define NTHR 1024
#define SL 257                // Ls row stride (floats)
#define SA 260                // As2 row stride (floats)

typedef float f32x2 __attribute__((ext_vector_type(2)));

__device__ __forceinline__ f32x2 pk_mul_lo(f32x2 a, f32x2 b) {
    f32x2 d;
    asm("v_pk_mul_f32 %0, %1, %2 op_sel:[0,0] op_sel_hi:[1,0]"
        : "=v"(d) : "v"(a), "v"(b));
    return d;
}
__device__ __forceinline__ f32x2 pk_mul_hi(f32x2 a, f32x2 b) {
    f32x2 d;
    asm("v_pk_mul_f32 %0, %1, %2 op_sel:[0,1] op_sel_hi:[1,1]"
        : "=v"(d) : "v"(a), "v"(b));
    return d;
}
__device__ __forceinline__ f32x2 pk_add(f32x2 a, f32x2 b) {
    f32x2 d;
    asm("v_pk_add_f32 %0, %1, %2" : "=v"(d) : "v"(a), "v"(b));
    return d;
}

// ---- kernel 0: pre-transform W into chunked, lane-linear slab image (as r6).
// Slab s = (e>>5)*2 + ((e>>4)&1), slot lane = (e&15)*4 + l.
// Bt[c][s*256 + lane*4 + q] = W[e][16c + 4q + l]
__global__ __launch_bounds__(256) void transform_kernel(
    const float* __restrict__ wgt, float* __restrict__ Bt)
{
    const int c    = blockIdx.x >> 2;
    const int qt   = blockIdx.x & 3;
    const int slot = qt * 256 + threadIdx.x;      // 0..1023
    const int s    = slot >> 6;                   // slab 0..15
    const int lane = slot & 63;
    const int em   = lane >> 2;
    const int l    = lane & 3;
    const int e    = (s >> 1) * 32 + (s & 1) * 16 + em;
    const float* src = wgt + (size_t)e * KD + 16 * c + l;
    float4 v = make_float4(src[0], src[4], src[8], src[12]);   // q = 0..3
    *(float4*)(Bt + (size_t)c * CHUNK_DW + slot * 4) = v;
}

typedef __attribute__((address_space(1))) const void GV;
typedef __attribute__((address_space(3))) void LV;
__device__ __forceinline__ void gld_lds16(const float* g, float* l) {
    __builtin_amdgcn_global_load_lds((GV*)g, (LV*)l, 16, 0, 0);
}

// Bit-exact numpy npyv(SSE3,no-FMA) einsum; lane-chains split across thread
// quads (l=tid&3). 1024 threads: 2 token-pairs x 8 experts per thread ->
// accumulator fits arch VGPRs. Single-barrier K loop with counted vmcnt:
// B loads stay in flight across the barrier (never drained to 0 mid-loop).
__global__ __launch_bounds__(NTHR)
__attribute__((amdgpu_waves_per_eu(4, 4)))
void gate_kernel(
    const float* __restrict__ hid, const float* __restrict__ Bt,
    float* __restrict__ out, float* __restrict__ cnt, float* __restrict__ prb)
{
    __shared__ union { float bs[2][2 * CHUNK_DW]; float ls[TM][SL]; } sh;
    __shared__ float As2[2][4][SA];   // [buf][l][pair*16 + q*2 + par]
    __shared__ float maxS[TM], sumS[TM], invS[TM];

    const int tid  = threadIdx.x;
    const int lane = tid & 63;
    const int w    = tid >> 6;             // wave 0..15
    const int l    = tid & 3;
    const int eg   = (tid >> 2) & 31;
    const int tg   = tid >> 7;             // token group 0..7 (4 tokens each)
    const int h    = w & 1;                // expert half within slab pair
    const int t0   = blockIdx.x * TM;

    f32x2 acc2[2][8];                      // [token-pair][j]  (32 VGPRs)
#pragma unroll
    for (int i = 0; i < 2; ++i)
#pragma unroll
        for (int j = 0; j < 8; ++j) acc2[i][j] = (f32x2){0.f, 0.f};

    // ---- A staging: threads 0..255 = (32 tokens x 8 q-octets); float4 = l 0..3
    const bool aact = (tid < 256);
    const int  at   = tid >> 3;            // token 0..31
    const int  aq   = tid & 7;             // q-octet 0..7
    float av[4];

    auto stageA_load = [&](int c) {        // c in BK=32 units; 1 vmem op
        if (aact)
            *(float4*)av = *(const float4*)(hid + (size_t)(t0 + at) * KD + 32 * c + 4 * aq);
    };
    auto stageA_write = [&](int buf) {
        if (aact) {
            const int base = (at >> 1) * 16 + aq * 2 + (at & 1);
#pragma unroll
            for (int ll = 0; ll < 4; ++ll)
                As2[buf][ll][base] = av[ll];
        }
    };
    auto stageB = [&](int c, int buf) {    // 2 vmem ops per thread
        const float* src = Bt + (size_t)(2 * c) * CHUNK_DW + tid * 4;
        float* dst = &sh.bs[buf][tid * 4];
        gld_lds16(src, dst);
        gld_lds16(src + 4096, dst + 4096);
    };

    // ---- prologue: A(0) -> LDS, B(0) in flight ----
    stageA_load(0);
    asm volatile("s_waitcnt vmcnt(0)" ::: "memory");
    stageA_write(0);
    stageB(0, 0);
    int cur = 0;

#pragma unroll 1
    for (int c = 0; c < NCHUNK; ++c) {
        const int nxt = cur ^ 1;
        const bool more = (c + 1 < NCHUNK);

        if (more) stageA_load(c + 1);      // A(c+1) -> regs (oldest after B(c))

        // wait B(c) complete (A(c+1) may stay in flight); drain lgkm so the
        // previous ds_write of As2[cur] is visible across waves at the barrier
        if (more && w < 4) asm volatile("s_waitcnt vmcnt(1) lgkmcnt(0)" ::: "memory");
        else               asm volatile("s_waitcnt vmcnt(0) lgkmcnt(0)" ::: "memory");
        __builtin_amdgcn_s_barrier();      // all waves: bs[cur]/As2[cur] ready,
                                           // all done reading bs[nxt]
        if (more) stageB(c + 1, nxt);      // DMA into bs[nxt] under the MACs

#pragma unroll
        for (int j16 = 0; j16 < 2; ++j16) {    // 16-blocks in ascending k
            f32x2 aQ[2][4];                    // [tp][q] token-pair fragments
#pragma unroll
            for (int tp = 0; tp < 2; ++tp) {
                const f32x2* ap = (const f32x2*)&As2[cur][l][(tg * 2 + tp) * 16 + j16 * 8];
                aQ[tp][0] = ap[0];
                aQ[tp][1] = ap[1];
                aQ[tp][2] = ap[2];
                aQ[tp][3] = ap[3];
            }
#pragma unroll
            for (int j = 0; j < 8; ++j) {
                const float4 b = *(const float4*)
                    &sh.bs[cur][j16 * CHUNK_DW + ((j * 2 + h) << 8) + (lane << 2)];
                const f32x2 b01 = (f32x2){b.x, b.y};   // {q0, q1}
                const f32x2 b23 = (f32x2){b.z, b.w};   // {q2, q3}
#pragma unroll
                for (int tp = 0; tp < 2; ++tp) {
                    f32x2 s = acc2[tp][j];
                    s = pk_add(pk_mul_hi(aQ[tp][3], b23), s);   // q=3
                    s = pk_add(pk_mul_lo(aQ[tp][2], b23), s);   // q=2
                    s = pk_add(pk_mul_hi(aQ[tp][1], b01), s);   // q=1
                    s = pk_add(pk_mul_lo(aQ[tp][0], b01), s);   // q=0
                    acc2[tp][j] = s;
                }
            }
        }

        if (more) {
            if (w < 4) asm volatile("s_waitcnt vmcnt(2)" ::: "memory");  // A(c+1) done
            stageA_write(nxt);             // B(c+1)'s 2 ops still in flight
        }
        cur = nxt;
    }

    // ---- combine lane-chains: (s0+s1)+(s2+s3) per component ----
    __syncthreads();                       // full drain before ls-union reuse
#pragma unroll
    for (int tp = 0; tp < 2; ++tp)
#pragma unroll
        for (int j = 0; j < 8; ++j) {
            float sx = acc2[tp][j].x, sy = acc2[tp][j].y;
            sx = __fadd_rn(sx, __shfl_xor(sx, 1));
            sx = __fadd_rn(sx, __shfl_xor(sx, 2));
            sy = __fadd_rn(sy, __shfl_xor(sy, 1));
            sy = __fadd_rn(sy, __shfl_xor(sy, 2));
            if (l == 0) {
                sh.ls[tg * 4 + 2 * tp][eg + 32 * j]     = sx;
                sh.ls[tg * 4 + 2 * tp + 1][eg + 32 * j] = sy;
            }
        }
    if (tid < TM) sumS[tid] = 0.f;
    __syncthreads();

    // ---- per-token top-k (threads 0..31), fp32 bit-exact ----
    if (tid < TM) {
        const float* lr = &sh.ls[tid][0];
        float tv[8]; int ti[8];
#pragma unroll
        for (int j = 0; j < 8; ++j) { tv[j] = -1e30f; ti[j] = 0; }
        float rowmax = -1e30f;

        auto ins8 = [&](float v, int idx) {
#pragma unroll
            for (int p = 0; p < 8; ++p) {
                if (v > tv[p]) {
#pragma unroll
                    for (int q = 7; q > p; --q) { tv[q] = tv[q - 1]; ti[q] = ti[q - 1]; }
                    tv[p] = v; ti[p] = idx;
                    break;
                }
            }
        };

#pragma unroll 1
        for (int g = 0; g < 8; ++g) {
            float v0 = -1e30f, v1 = -1e30f, v2 = -1e30f, v3 = -1e30f;
            int   i0 = 0, i1 = 0, i2 = 0, i3 = 0;
            for (int j = 0; j < 32; ++j) {
                const float v = lr[g * 32 + j];
                if (v > v0)      { v3=v2;i3=i2; v2=v1;i2=i1; v1=v0;i1=i0; v0=v;i0=j; }
                else if (v > v1) { v3=v2;i3=i2; v2=v1;i2=i1; v1=v;i1=j; }
                else if (v > v2) { v3=v2;i3=i2; v2=v;i2=j; }
                else if (v > v3) { v3=v;i3=j; }
            }
            rowmax = fmaxf(rowmax, v0);
            ins8(v0, g * 32 + i0);
            ins8(v1, g * 32 + i1);
            ins8(v2, g * 32 + i2);
            ins8(v3, g * 32 + i3);
        }

        const float s01 = __fadd_rn(tv[0], tv[1]);
        const float s23 = __fadd_rn(tv[2], tv[3]);
        const float s45 = __fadd_rn(tv[4], tv[5]);
        const float s67 = __fadd_rn(tv[6], tv[7]);
        float s = __fadd_rn(__fadd_rn(s01, s23), __fadd_rn(s45, s67));
        s = __fadd_rn(s, 1e-20f);

        const size_t tg2 = (size_t)(t0 + tid);
#pragma unroll
        for (int j = 0; j < 8; ++j) {
            out[tg2 * 8 + j]                    = (float)ti[j];
            out[(size_t)NTOK * 8 + tg2 * 8 + j] = __fdiv_rn(tv[j], s);
            atomicAdd(&cnt[ti[j]], 1.0f);
        }
        maxS[tid] = rowmax;
    }
    __syncthreads();

    // ---- per-token softmax denominator (32 threads per token) ----
    {
        const int t  = tid >> 5;           // 0..31
        const int c0 = (tid & 31) * 8;
        const float m = maxS[t];
        float part = 0.f;
#pragma unroll
        for (int j = 0; j < 8; ++j) part += __expf(sh.ls[t][c0 + j] - m);
        atomicAdd(&sumS[t], part);
    }
    __syncthreads();
    if (tid < TM) invS[tid] = 1.0f / sumS[tid];
    __syncthreads();

    // ---- per-expert softmax-prob partial over block tokens ----
    if (tid < NE) {
        float p = 0.f;
#pragma unroll
        for (int n = 0; n < TM; ++n) p += __expf(sh.ls[n][tid] - maxS[n]) * invS[n];
        atomicAdd(&prb[tid], p);
    }
}

__global__ void aux_kernel(const float* __restrict__ cnt,
                           const float* __restrict__ prb,
                           float* __restrict__ out)
{
    const int tid = threadIdx.x;
    float v = cnt[tid] * prb[tid];
#pragma unroll
    for (int off = 32; off; off >>= 1) v += __shfl_down(v, off, 64);
    __shared__ float ps[4];
    if ((tid & 63) == 0) ps[tid >> 6] = v;
    __syncthreads();
    if (tid == 0) {
        const float tot = ps[0] + ps[1] + ps[2] + ps[3];
        out[(size_t)NTOK * 8 * 2] = tot * (0.001f / (131072.0f * 16384.0f));
    }
}

extern "C" void kernel_launch(void* const* d_in, const int* in_sizes, int n_in,
                              void* d_out, int out_size, void* d_ws, size_t ws_size,
                              hipStream_t stream)
{
    (void)in_sizes; (void)n_in; (void)out_size; (void)ws_size;
    const float* hid = (const float*)d_in[0];
    const float* wgt = (const float*)d_in[1];
    float* out = (float*)d_out;
    float* cnt = (float*)d_ws;             // 256 f
    float* prb = cnt + NE;                 // 256 f
    float* Bt  = prb + NE;                 // 2 MB image (16B-aligned offset)

    hipMemsetAsync(d_ws, 0, 2 * NE * sizeof(float), stream);
    transform_kernel<<<512, 256, 0, stream>>>(wgt, Bt);
    gate_kernel<<<NTOK / TM, NTHR, 0, stream>>>(hid, Bt, out, cnt, prb);
    aux_kernel<<<1, 256, 0, stream>>>(cnt, prb, out);
}

// Round 13
// 671.219 us; speedup vs baseline: 3.5737x; 1.1318x over previous
//
#include <hip/hip_runtime.h>
#include <math.h>

#define NTOK 16384
#define KD   2048
#define NE   256
#define NCHUNK 128            // K step 16
#define CHUNK_DW 4096         // NE*16 dwords per 16-K chunk image
#define TM 16                 // tokens per block
#define NTHR 512
#define SL 257                // Ls row stride (floats)
#define SA 68                 // As2 per-l row stride (floats)

typedef float f32x2 __attribute__((ext_vector_type(2)));

__device__ __forceinline__ f32x2 pk_mul_lo(f32x2 a, f32x2 b) {
    f32x2 d;
    asm("v_pk_mul_f32 %0, %1, %2 op_sel:[0,0] op_sel_hi:[1,0]"
        : "=v"(d) : "v"(a), "v"(b));
    return d;
}
__device__ __forceinline__ f32x2 pk_mul_hi(f32x2 a, f32x2 b) {
    f32x2 d;
    asm("v_pk_mul_f32 %0, %1, %2 op_sel:[0,1] op_sel_hi:[1,1]"
        : "=v"(d) : "v"(a), "v"(b));
    return d;
}
__device__ __forceinline__ f32x2 pk_add(f32x2 a, f32x2 b) {
    f32x2 d;
    asm("v_pk_add_f32 %0, %1, %2" : "=v"(d) : "v"(a), "v"(b));
    return d;
}

// ---- kernel 0: pre-transform W into chunked, lane-linear slab image (as r6).
// Slab s = (e>>5)*2 + ((e>>4)&1), slot lane = (e&15)*4 + l.
// Bt[c][s*256 + lane*4 + q] = W[e][16c + 4q + l]
__global__ __launch_bounds__(256) void transform_kernel(
    const float* __restrict__ wgt, float* __restrict__ Bt)
{
    const int c    = blockIdx.x >> 2;
    const int qt   = blockIdx.x & 3;
    const int slot = qt * 256 + threadIdx.x;      // 0..1023
    const int s    = slot >> 6;                   // slab 0..15
    const int lane = slot & 63;
    const int em   = lane >> 2;
    const int l    = lane & 3;
    const int e    = (s >> 1) * 32 + (s & 1) * 16 + em;
    const float* src = wgt + (size_t)e * KD + 16 * c + l;
    float4 v = make_float4(src[0], src[4], src[8], src[12]);   // q = 0..3
    *(float4*)(Bt + (size_t)c * CHUNK_DW + slot * 4) = v;
}

typedef __attribute__((address_space(1))) const void GV;
typedef __attribute__((address_space(3))) void LV;
__device__ __forceinline__ void gld_lds16(const float* g, float* l) {
    __builtin_amdgcn_global_load_lds((GV*)g, (LV*)l, 16, 0, 0);
}

// Bit-exact numpy npyv(SSE3,no-FMA) einsum; lane-chains split across thread
// quads (l=tid&3). TM=16/BK=16/512thr: ~34.5KB LDS + ~58 VGPR demand ->
// 4 blocks/CU, 32 waves/CU (100% occupancy cap) to hide LDS/barrier stalls.
__global__ __launch_bounds__(NTHR) void gate_kernel(
    const float* __restrict__ hid, const float* __restrict__ Bt,
    float* __restrict__ out, float* __restrict__ cnt, float* __restrict__ prb)
{
    __shared__ union { float bs[2][CHUNK_DW]; float ls[TM][SL]; } sh;
    __shared__ float As2[2][4][SA];   // [buf][l][pair*8 + q*2 + par]
    __shared__ float maxS[TM], sumS[TM], invS[TM];

    const int tid  = threadIdx.x;
    const int lane = tid & 63;
    const int w    = tid >> 6;             // wave 0..7
    const int l    = tid & 3;
    const int eg   = (tid >> 2) & 31;
    const int tg   = tid >> 7;             // token group 0..3 (4 tokens each)
    const int h    = w & 1;                // expert half within slab pair
    const int t0   = blockIdx.x * TM;

    f32x2 acc2[2][8];                      // [token-pair][j]  (32 VGPRs)
#pragma unroll
    for (int i = 0; i < 2; ++i)
#pragma unroll
        for (int j = 0; j < 8; ++j) acc2[i][j] = (f32x2){0.f, 0.f};

    // ---- A staging: threads 0..63 = (16 tokens x 4 q); float4 = l 0..3 ----
    const bool aact = (tid < 64);
    const int  at   = tid >> 2;            // token 0..15
    const int  aq   = tid & 3;             // q 0..3
    float av[4];

    auto stageA_load = [&](int c) {        // c in BK=16 units
        if (aact)
            *(float4*)av = *(const float4*)(hid + (size_t)(t0 + at) * KD + 16 * c + 4 * aq);
    };
    auto stageA_write = [&](int buf) {
        if (aact) {
            const int base = (at >> 1) * 8 + aq * 2 + (at & 1);
#pragma unroll
            for (int ll = 0; ll < 4; ++ll)
                As2[buf][ll][base] = av[ll];
        }
    };
    auto stageB = [&](int c, int buf) {    // one 16-chunk image
        const float* src = Bt + (size_t)c * CHUNK_DW + tid * 4;
        float* dst = &sh.bs[buf][tid * 4];
        gld_lds16(src, dst);
        gld_lds16(src + 2048, dst + 2048);
    };

    stageA_load(0);
    stageB(0, 0);
    stageA_write(0);
    int cur = 0;

#pragma unroll 1
    for (int c = 0; c < NCHUNK; ++c) {
        __syncthreads();                       // cur buffers ready; nxt free
        const int nxt = cur ^ 1;
        if (c + 1 < NCHUNK) { stageA_load(c + 1); stageB(c + 1, nxt); }

        f32x2 aQ[2][4];                        // [tp][q] token-pair fragments
#pragma unroll
        for (int tp = 0; tp < 2; ++tp) {
            const float* ap = &As2[cur][l][(tg * 2 + tp) * 8];
            const float4 a0 = *(const float4*)(ap);       // q0,q1 pairs
            const float4 a1 = *(const float4*)(ap + 4);   // q2,q3 pairs
            aQ[tp][0] = (f32x2){a0.x, a0.y};
            aQ[tp][1] = (f32x2){a0.z, a0.w};
            aQ[tp][2] = (f32x2){a1.x, a1.y};
            aQ[tp][3] = (f32x2){a1.z, a1.w};
        }
#pragma unroll
        for (int j = 0; j < 8; ++j) {
            const float4 b = *(const float4*)
                &sh.bs[cur][((j * 2 + h) << 8) + (lane << 2)];
            const f32x2 b01 = (f32x2){b.x, b.y};   // {q0, q1}
            const f32x2 b23 = (f32x2){b.z, b.w};   // {q2, q3}
#pragma unroll
            for (int tp = 0; tp < 2; ++tp) {
                f32x2 s = acc2[tp][j];
                s = pk_add(pk_mul_hi(aQ[tp][3], b23), s);   // q=3
                s = pk_add(pk_mul_lo(aQ[tp][2], b23), s);   // q=2
                s = pk_add(pk_mul_hi(aQ[tp][1], b01), s);   // q=1
                s = pk_add(pk_mul_lo(aQ[tp][0], b01), s);   // q=0
                acc2[tp][j] = s;
            }
        }
        if (c + 1 < NCHUNK) stageA_write(nxt);
        cur = nxt;
    }

    // ---- combine lane-chains: (s0+s1)+(s2+s3) per component ----
    __syncthreads();                       // all waves done with sh.bs
#pragma unroll
    for (int tp = 0; tp < 2; ++tp)
#pragma unroll
        for (int j = 0; j < 8; ++j) {
            float sx = acc2[tp][j].x, sy = acc2[tp][j].y;
            sx = __fadd_rn(sx, __shfl_xor(sx, 1));
            sx = __fadd_rn(sx, __shfl_xor(sx, 2));
            sy = __fadd_rn(sy, __shfl_xor(sy, 1));
            sy = __fadd_rn(sy, __shfl_xor(sy, 2));
            if (l == 0) {
                sh.ls[tg * 4 + 2 * tp][eg + 32 * j]     = sx;
                sh.ls[tg * 4 + 2 * tp + 1][eg + 32 * j] = sy;
            }
        }
    if (tid < TM) sumS[tid] = 0.f;
    __syncthreads();

    // ---- per-token top-k (threads 0..15), fp32 bit-exact ----
    if (tid < TM) {
        const float* lr = &sh.ls[tid][0];
        float tv[8]; int ti[8];
#pragma unroll
        for (int j = 0; j < 8; ++j) { tv[j] = -1e30f; ti[j] = 0; }
        float rowmax = -1e30f;

        auto ins8 = [&](float v, int idx) {
#pragma unroll
            for (int p = 0; p < 8; ++p) {
                if (v > tv[p]) {
#pragma unroll
                    for (int q = 7; q > p; --q) { tv[q] = tv[q - 1]; ti[q] = ti[q - 1]; }
                    tv[p] = v; ti[p] = idx;
                    break;
                }
            }
        };

#pragma unroll 1
        for (int g = 0; g < 8; ++g) {
            float v0 = -1e30f, v1 = -1e30f, v2 = -1e30f, v3 = -1e30f;
            int   i0 = 0, i1 = 0, i2 = 0, i3 = 0;
            for (int j = 0; j < 32; ++j) {
                const float v = lr[g * 32 + j];
                if (v > v0)      { v3=v2;i3=i2; v2=v1;i2=i1; v1=v0;i1=i0; v0=v;i0=j; }
                else if (v > v1) { v3=v2;i3=i2; v2=v1;i2=i1; v1=v;i1=j; }
                else if (v > v2) { v3=v2;i3=i2; v2=v;i2=j; }
                else if (v > v3) { v3=v;i3=j; }
            }
            rowmax = fmaxf(rowmax, v0);
            ins8(v0, g * 32 + i0);
            ins8(v1, g * 32 + i1);
            ins8(v2, g * 32 + i2);
            ins8(v3, g * 32 + i3);
        }

        const float s01 = __fadd_rn(tv[0], tv[1]);
        const float s23 = __fadd_rn(tv[2], tv[3]);
        const float s45 = __fadd_rn(tv[4], tv[5]);
        const float s67 = __fadd_rn(tv[6], tv[7]);
        float s = __fadd_rn(__fadd_rn(s01, s23), __fadd_rn(s45, s67));
        s = __fadd_rn(s, 1e-20f);

        const size_t tg2 = (size_t)(t0 + tid);
#pragma unroll
        for (int j = 0; j < 8; ++j) {
            out[tg2 * 8 + j]                    = (float)ti[j];
            out[(size_t)NTOK * 8 + tg2 * 8 + j] = __fdiv_rn(tv[j], s);
            atomicAdd(&cnt[ti[j]], 1.0f);
        }
        maxS[tid] = rowmax;
    }
    __syncthreads();

    // ---- per-token softmax denominator (32 threads per token) ----
    {
        const int t  = tid >> 5;           // 0..15
        const int c0 = (tid & 31) * 8;
        const float m = maxS[t];
        float part = 0.f;
#pragma unroll
        for (int j = 0; j < 8; ++j) part += __expf(sh.ls[t][c0 + j] - m);
        atomicAdd(&sumS[t], part);
    }
    __syncthreads();
    if (tid < TM) invS[tid] = 1.0f / sumS[tid];
    __syncthreads();

    // ---- per-expert softmax-prob partial over block tokens ----
    if (tid < NE) {
        float p = 0.f;
#pragma unroll
        for (int n = 0; n < TM; ++n) p += __expf(sh.ls[n][tid] - maxS[n]) * invS[n];
        atomicAdd(&prb[tid], p);
    }
}

__global__ void aux_kernel(const float* __restrict__ cnt,
                           const float* __restrict__ prb,
                           float* __restrict__ out)
{
    const int tid = threadIdx.x;
    float v = cnt[tid] * prb[tid];
#pragma unroll
    for (int off = 32; off; off >>= 1) v += __shfl_down(v, off, 64);
    __shared__ float ps[4];
    if ((tid & 63) == 0) ps[tid >> 6] = v;
    __syncthreads();
    if (tid == 0) {
        const float tot = ps[0] + ps[1] + ps[2] + ps[3];
        out[(size_t)NTOK * 8 * 2] = tot * (0.001f / (131072.0f * 16384.0f));
    }
}

extern "C" void kernel_launch(void* const* d_in, const int* in_sizes, int n_in,
                              void* d_out, int out_size, void* d_ws, size_t ws_size,
                              hipStream_t stream)
{
    (void)in_sizes; (void)n_in; (void)out_size; (void)ws_size;
    const float* hid = (const float*)d_in[0];
    const float* wgt = (const float*)d_in[1];
    float* out = (float*)d_out;
    float* cnt = (float*)d_ws;             // 256 f
    float* prb = cnt + NE;                 // 256 f
    float* Bt  = prb + NE;                 // 2 MB image (16B-aligned offset)

    hipMemsetAsync(d_ws, 0, 2 * NE * sizeof(float), stream);
    transform_kernel<<<512, 256, 0, stream>>>(wgt, Bt);
    gate_kernel<<<NTOK / TM, NTHR, 0, stream>>>(hid, Bt, out, cnt, prb);
    aux_kernel<<<1, 256, 0, stream>>>(cnt, prb, out);
}

// Round 14
// 554.097 us; speedup vs baseline: 4.3291x; 1.2114x over previous
//
#include <hip/hip_runtime.h>
#include <math.h>

#define NTOK 16384
#define KD   2048
#define NE   256
#define BM   64
#define NSTEP 64              // K-steps of 32
#define EPS  2.5e-4f

using bf16x8 = __attribute__((ext_vector_type(8))) short;
using f32x16 = __attribute__((ext_vector_type(16))) float;
using u16 = unsigned short;
using u32 = unsigned int;

__device__ __forceinline__ u16 f2bf(float x) {
    u32 u = __float_as_uint(x);
    return (u16)((u + 0x7FFFu + ((u >> 16) & 1u)) >> 16);
}
__device__ __forceinline__ float bf2f(u16 h) {
    return __uint_as_float(((u32)h) << 16);
}

// ---- K0: split W into bf16 hi/lo images, K-step-major: img[c][e][kk] ----
__global__ __launch_bounds__(256) void wsplit_kernel(
    const float* __restrict__ wgt, u16* __restrict__ Whi, u16* __restrict__ Wlo)
{
    const int idx = blockIdx.x * 256 + threadIdx.x;   // e*2048+k
    const int e = idx >> 11, k = idx & 2047;
    const int c = k >> 5, kk = k & 31;
    const float w = wgt[idx];
    const u16 hi = f2bf(w);
    const u16 lo = f2bf(w - bf2f(hi));
    const int off = c * 8192 + e * 32 + kk;
    Whi[off] = hi; Wlo[off] = lo;
}

// ---- K1: MFMA split-GEMM (fast logits) + top-k + flags + softmax partials ----
__global__ __launch_bounds__(256) void gate_kernel(
    const float* __restrict__ hid, const u16* __restrict__ Whi, const u16* __restrict__ Wlo,
    float* __restrict__ out, float* __restrict__ cnt, float* __restrict__ prb,
    int* __restrict__ flagcnt, int* __restrict__ flaglist)
{
    __shared__ union {
        struct {
            u16 ah[2][64][40];
            u16 al[2][64][40];
            u16 bh[2][256][40];
            u16 bl[2][256][40];
        } st;
        float ls[64][257];
    } sh;
    __shared__ float maxS[64], sumS[64], invS[64];

    const int tid  = threadIdx.x;
    const int lane = tid & 63;
    const int wv   = tid >> 6;
    const int ln31 = lane & 31;
    const int kh8  = (lane >> 5) * 8;
    const int t0   = blockIdx.x * BM;

    f32x16 acc[2][2];
#pragma unroll
    for (int mf = 0; mf < 2; ++mf)
#pragma unroll
        for (int nf = 0; nf < 2; ++nf)
#pragma unroll
            for (int r = 0; r < 16; ++r) acc[mf][nf][r] = 0.f;

    // staging registers
    float4 arg0, arg1;
    uint4 brgh[4], brgl[4];
    const int am  = tid >> 2;          // token row 0..63
    const int akq = (tid & 3) * 8;     // k-octet

    auto loadA = [&](int c) {
        const float* p = hid + (size_t)(t0 + am) * KD + c * 32 + akq;
        arg0 = *(const float4*)p;
        arg1 = *(const float4*)(p + 4);
    };
    auto loadB = [&](int c) {
        const u16* ph = Whi + c * 8192 + tid * 32;
        const u16* pl = Wlo + c * 8192 + tid * 32;
#pragma unroll
        for (int i = 0; i < 4; ++i) {
            brgh[i] = *(const uint4*)(ph + i * 8);
            brgl[i] = *(const uint4*)(pl + i * 8);
        }
    };
    auto writeA = [&](int buf) {
        float f[8] = {arg0.x, arg0.y, arg0.z, arg0.w, arg1.x, arg1.y, arg1.z, arg1.w};
        u16 hi[8], lo[8];
#pragma unroll
        for (int i = 0; i < 8; ++i) {
            hi[i] = f2bf(f[i]);
            lo[i] = f2bf(f[i] - bf2f(hi[i]));
        }
#pragma unroll
        for (int i = 0; i < 8; ++i) {
            sh.st.ah[buf][am][akq + i] = hi[i];
            sh.st.al[buf][am][akq + i] = lo[i];
        }
    };
    auto writeB = [&](int buf) {
#pragma unroll
        for (int i = 0; i < 4; ++i) {
            *(uint4*)&sh.st.bh[buf][tid][i * 8] = brgh[i];
            *(uint4*)&sh.st.bl[buf][tid][i * 8] = brgl[i];
        }
    };

    loadA(0); loadB(0);
    writeA(0); writeB(0);
    int cur = 0;

#pragma unroll 1
    for (int c = 0; c < NSTEP; ++c) {
        __syncthreads();                    // buf[cur] visible; buf[nxt] free
        const int nxt = cur ^ 1;
        if (c + 1 < NSTEP) { loadA(c + 1); loadB(c + 1); }

#pragma unroll
        for (int s = 0; s < 2; ++s) {       // two K=16 sub-steps
            bf16x8 ah[2], al2[2], bh[2], bl2[2];
#pragma unroll
            for (int mf = 0; mf < 2; ++mf) {
                const int r = mf * 32 + ln31;
                ah[mf]  = *(const bf16x8*)&sh.st.ah[cur][r][s * 16 + kh8];
                al2[mf] = *(const bf16x8*)&sh.st.al[cur][r][s * 16 + kh8];
            }
#pragma unroll
            for (int nf = 0; nf < 2; ++nf) {
                const int r = wv * 64 + nf * 32 + ln31;
                bh[nf]  = *(const bf16x8*)&sh.st.bh[cur][r][s * 16 + kh8];
                bl2[nf] = *(const bf16x8*)&sh.st.bl[cur][r][s * 16 + kh8];
            }
#pragma unroll
            for (int mf = 0; mf < 2; ++mf)
#pragma unroll
                for (int nf = 0; nf < 2; ++nf) {
                    acc[mf][nf] = __builtin_amdgcn_mfma_f32_32x32x16_bf16(ah[mf],  bh[nf],  acc[mf][nf], 0, 0, 0);
                    acc[mf][nf] = __builtin_amdgcn_mfma_f32_32x32x16_bf16(ah[mf],  bl2[nf], acc[mf][nf], 0, 0, 0);
                    acc[mf][nf] = __builtin_amdgcn_mfma_f32_32x32x16_bf16(al2[mf], bh[nf],  acc[mf][nf], 0, 0, 0);
                }
        }
        if (c + 1 < NSTEP) { writeA(nxt); writeB(nxt); }
        cur = nxt;
    }

    // ---- dump logits (C/D: col=lane&31, row=(r&3)+8*(r>>2)+4*(lane>>5)) ----
    __syncthreads();                        // all MFMA reads of stage done
#pragma unroll
    for (int mf = 0; mf < 2; ++mf)
#pragma unroll
        for (int nf = 0; nf < 2; ++nf) {
            const int col = wv * 64 + nf * 32 + ln31;
#pragma unroll
            for (int r = 0; r < 16; ++r) {
                const int row = mf * 32 + (r & 3) + 8 * (r >> 2) + 4 * (lane >> 5);
                sh.ls[row][col] = acc[mf][nf][r];
            }
        }
    if (tid < 64) sumS[tid] = 0.f;
    __syncthreads();

    // ---- per-token top-k + margin flags (threads 0..63) ----
    if (tid < 64) {
        const float* lr = &sh.ls[tid][0];
        float tv[9]; int ti[9];
#pragma unroll
        for (int j = 0; j < 9; ++j) { tv[j] = -1e30f; ti[j] = 0; }
        float gv3[8], gv4[8];
        float rowmax = -1e30f;

        auto ins9 = [&](float v, int idx) {
#pragma unroll
            for (int p = 0; p < 9; ++p) {
                if (v > tv[p]) {
#pragma unroll
                    for (int q = 8; q > p; --q) { tv[q] = tv[q - 1]; ti[q] = ti[q - 1]; }
                    tv[p] = v; ti[p] = idx;
                    break;
                }
            }
        };

#pragma unroll 1
        for (int g = 0; g < 8; ++g) {
            float v0 = -1e30f, v1 = -1e30f, v2 = -1e30f, v3 = -1e30f, v4 = -1e30f;
            int   i0 = 0, i1 = 0, i2 = 0, i3 = 0;
            for (int j = 0; j < 32; ++j) {
                const float v = lr[g * 32 + j];
                if (v > v0)      { v4=v3; v3=v2;i3=i2; v2=v1;i2=i1; v1=v0;i1=i0; v0=v;i0=j; }
                else if (v > v1) { v4=v3; v3=v2;i3=i2; v2=v1;i2=i1; v1=v;i1=j; }
                else if (v > v2) { v4=v3; v3=v2;i3=i2; v2=v;i2=j; }
                else if (v > v3) { v4=v3; v3=v;i3=j; }
                else if (v > v4) { v4=v; }
            }
            rowmax = fmaxf(rowmax, v0);
            gv3[g] = v3; gv4[g] = v4;
            ins9(v0, g * 32 + i0);
            ins9(v1, g * 32 + i1);
            ins9(v2, g * 32 + i2);
            ins9(v3, g * 32 + i3);
        }

        bool flag = false;
#pragma unroll
        for (int r = 0; r < 8; ++r)
            if (tv[r] - tv[r + 1] < EPS) flag = true;
#pragma unroll
        for (int g = 0; g < 8; ++g)
            if (gv3[g] - gv4[g] < EPS && gv3[g] > tv[7] - EPS) flag = true;

        const float s01 = __fadd_rn(tv[0], tv[1]);
        const float s23 = __fadd_rn(tv[2], tv[3]);
        const float s45 = __fadd_rn(tv[4], tv[5]);
        const float s67 = __fadd_rn(tv[6], tv[7]);
        float s = __fadd_rn(__fadd_rn(s01, s23), __fadd_rn(s45, s67));
        s = __fadd_rn(s, 1e-20f);

        const size_t tg2 = (size_t)(t0 + tid);
#pragma unroll
        for (int j = 0; j < 8; ++j) {
            out[tg2 * 8 + j]                    = (float)ti[j];
            out[(size_t)NTOK * 8 + tg2 * 8 + j] = __fdiv_rn(tv[j], s);
            atomicAdd(&cnt[ti[j]], 1.0f);
        }
        if (flag) {
            const int fi = atomicAdd(flagcnt, 1);
            flaglist[fi] = t0 + tid;
        }
        maxS[tid] = rowmax;
    }
    __syncthreads();

    // ---- softmax denominator (4 threads per token) ----
    {
        const int t  = tid & 63;
        const int c0 = (tid >> 6) * 64;
        const float m = maxS[t];
        float part = 0.f;
#pragma unroll
        for (int j = 0; j < 64; ++j) part += __expf(sh.ls[t][c0 + j] - m);
        atomicAdd(&sumS[t], part);
    }
    __syncthreads();
    if (tid < 64) invS[tid] = 1.0f / sumS[tid];
    __syncthreads();

    // ---- per-expert softmax-prob partial over block tokens ----
    {
        float p = 0.f;
#pragma unroll
        for (int n = 0; n < 64; ++n) p += __expf(sh.ls[n][tid] - maxS[n]) * invS[n];
        atomicAdd(&prb[tid], p);
    }
}

// ---- K2: bit-exact numpy-DAG recompute of flagged tokens (8 per block) ----
__global__ __launch_bounds__(256) void exact_kernel(
    const float* __restrict__ hid, const float* __restrict__ wgt,
    float* __restrict__ out, float* __restrict__ cnt,
    const int* __restrict__ flagcnt, const int* __restrict__ flaglist)
{
    const int fn = *flagcnt;
    const int base = blockIdx.x * 8;
    if (base >= fn) return;
    const int nt = min(8, fn - base);

    __shared__ float wch[256 * 17];
    __shared__ float hch[8 * 17];
    __shared__ float exls[8][257];
    __shared__ int tk[8];

    const int tid = threadIdx.x;
    const int tg  = tid >> 7;            // 0..1 (4 tokens each)
    const int eg  = (tid >> 2) & 31;     // 0..31
    const int l   = tid & 3;

    if (tid < 8) tk[tid] = (tid < nt) ? flaglist[base + tid] : flaglist[base];
    __syncthreads();

    float accq[4][8];                    // [token][expert j] chain-l partials
#pragma unroll
    for (int i = 0; i < 4; ++i)
#pragma unroll
        for (int j = 0; j < 8; ++j) accq[i][j] = 0.f;

#pragma unroll 1
    for (int c = 0; c < 128; ++c) {      // 16-blocks ascending
        __syncthreads();
        // stage W chunk: 256 e x 16 k
        {
            const float* p = wgt + (size_t)tid * KD + c * 16;
            float4 w0 = *(const float4*)(p);
            float4 w1 = *(const float4*)(p + 4);
            float4 w2 = *(const float4*)(p + 8);
            float4 w3 = *(const float4*)(p + 12);
            float* wr = &wch[tid * 17];
            wr[0]=w0.x; wr[1]=w0.y; wr[2]=w0.z; wr[3]=w0.w;
            wr[4]=w1.x; wr[5]=w1.y; wr[6]=w1.z; wr[7]=w1.w;
            wr[8]=w2.x; wr[9]=w2.y; wr[10]=w2.z; wr[11]=w2.w;
            wr[12]=w3.x; wr[13]=w3.y; wr[14]=w3.z; wr[15]=w3.w;
        }
        // stage h chunk: 8 tok x 16 k
        if (tid < 128) {
            const int tok = tid >> 4, k = tid & 15;
            hch[tok * 17 + k] = hid[(size_t)tk[tok] * KD + c * 16 + k];
        }
        __syncthreads();

        // chain: s = p(q0) + (p(q1) + (p(q2) + (p(q3) + s)))  -> q desc
#pragma unroll
        for (int q = 3; q >= 0; --q) {
            const int k = 4 * q + l;
            float hv[4], wv2[8];
#pragma unroll
            for (int i = 0; i < 4; ++i) hv[i] = hch[(tg * 4 + i) * 17 + k];
#pragma unroll
            for (int j = 0; j < 8; ++j) wv2[j] = wch[(j * 32 + eg) * 17 + k];
#pragma unroll
            for (int i = 0; i < 4; ++i)
#pragma unroll
                for (int j = 0; j < 8; ++j)
                    accq[i][j] = __fadd_rn(__fmul_rn(hv[i], wv2[j]), accq[i][j]);
        }
    }

    // combine lane-chains (s0+s1)+(s2+s3)
    __syncthreads();
#pragma unroll
    for (int i = 0; i < 4; ++i)
#pragma unroll
        for (int j = 0; j < 8; ++j) {
            float v = accq[i][j];
            v = __fadd_rn(v, __shfl_xor(v, 1));
            v = __fadd_rn(v, __shfl_xor(v, 2));
            if (l == 0) exls[tg * 4 + i][j * 32 + eg] = v;
        }
    __syncthreads();

    // exact top-k per token (threads 0..7), overwrite out, fix cnt
    if (tid < nt) {
        const float* lr = &exls[tid][0];
        float tv[8]; int ti[8];
#pragma unroll
        for (int j = 0; j < 8; ++j) { tv[j] = -1e30f; ti[j] = 0; }

        auto ins8 = [&](float v, int idx) {
#pragma unroll
            for (int p = 0; p < 8; ++p) {
                if (v > tv[p]) {
#pragma unroll
                    for (int q = 7; q > p; --q) { tv[q] = tv[q - 1]; ti[q] = ti[q - 1]; }
                    tv[p] = v; ti[p] = idx;
                    break;
                }
            }
        };

#pragma unroll 1
        for (int g = 0; g < 8; ++g) {
            float v0 = -1e30f, v1 = -1e30f, v2 = -1e30f, v3 = -1e30f;
            int   i0 = 0, i1 = 0, i2 = 0, i3 = 0;
            for (int j = 0; j < 32; ++j) {
                const float v = lr[g * 32 + j];
                if (v > v0)      { v3=v2;i3=i2; v2=v1;i2=i1; v1=v0;i1=i0; v0=v;i0=j; }
                else if (v > v1) { v3=v2;i3=i2; v2=v1;i2=i1; v1=v;i1=j; }
                else if (v > v2) { v3=v2;i3=i2; v2=v;i2=j; }
                else if (v > v3) { v3=v;i3=j; }
            }
            ins8(v0, g * 32 + i0);
            ins8(v1, g * 32 + i1);
            ins8(v2, g * 32 + i2);
            ins8(v3, g * 32 + i3);
        }

        const float s01 = __fadd_rn(tv[0], tv[1]);
        const float s23 = __fadd_rn(tv[2], tv[3]);
        const float s45 = __fadd_rn(tv[4], tv[5]);
        const float s67 = __fadd_rn(tv[6], tv[7]);
        float s = __fadd_rn(__fadd_rn(s01, s23), __fadd_rn(s45, s67));
        s = __fadd_rn(s, 1e-20f);

        const size_t gt = (size_t)tk[tid];
#pragma unroll
        for (int j = 0; j < 8; ++j) {
            const int oldi = (int)out[gt * 8 + j];
            if (oldi != ti[j]) {
                atomicAdd(&cnt[oldi], -1.0f);
                atomicAdd(&cnt[ti[j]], 1.0f);
            }
            out[gt * 8 + j]                    = (float)ti[j];
            out[(size_t)NTOK * 8 + gt * 8 + j] = __fdiv_rn(tv[j], s);
        }
    }
}

__global__ void aux_kernel(const float* __restrict__ cnt,
                           const float* __restrict__ prb,
                           float* __restrict__ out)
{
    const int tid = threadIdx.x;
    float v = cnt[tid] * prb[tid];
#pragma unroll
    for (int off = 32; off; off >>= 1) v += __shfl_down(v, off, 64);
    __shared__ float ps[4];
    if ((tid & 63) == 0) ps[tid >> 6] = v;
    __syncthreads();
    if (tid == 0) {
        const float tot = ps[0] + ps[1] + ps[2] + ps[3];
        out[(size_t)NTOK * 8 * 2] = tot * (0.001f / (131072.0f * 16384.0f));
    }
}

extern "C" void kernel_launch(void* const* d_in, const int* in_sizes, int n_in,
                              void* d_out, int out_size, void* d_ws, size_t ws_size,
                              hipStream_t stream)
{
    (void)in_sizes; (void)n_in; (void)out_size; (void)ws_size;
    const float* hid = (const float*)d_in[0];
    const float* wgt = (const float*)d_in[1];
    float* out = (float*)d_out;

    float* cnt      = (float*)d_ws;                  // 256 f
    float* prb      = cnt + NE;                      // 256 f
    int*   flagcnt  = (int*)(prb + NE);              // 1 i (+63 pad)
    int*   flaglist = flagcnt + 64;                  // 16384 i
    u16*   Whi      = (u16*)(flaglist + NTOK);       // 1 MB
    u16*   Wlo      = Whi + (size_t)NE * KD;         // 1 MB

    hipMemsetAsync(d_ws, 0, (2 * NE + 64) * sizeof(float), stream);
    wsplit_kernel<<<2048, 256, 0, stream>>>(wgt, Whi, Wlo);
    gate_kernel<<<NTOK / BM, 256, 0, stream>>>(hid, Whi, Wlo, out, cnt, prb, flagcnt, flaglist);
    exact_kernel<<<NTOK / 8, 256, 0, stream>>>(hid, wgt, out, cnt, flagcnt, flaglist);
    aux_kernel<<<1, 256, 0, stream>>>(cnt, prb, out);
}

// Round 15
// 493.229 us; speedup vs baseline: 4.8633x; 1.1234x over previous
//
#include <hip/hip_runtime.h>
#include <math.h>

#define NTOK 16384
#define KD   2048
#define NE   256
#define BM   32
#define NSTEP 64              // K-steps of 32
#define EPS  2.5e-4f

using bf16x8 = __attribute__((ext_vector_type(8))) short;
using f32x16 = __attribute__((ext_vector_type(16))) float;
using u16 = unsigned short;
using u32 = unsigned int;

__device__ __forceinline__ u16 f2bf(float x) {
    u32 u = __float_as_uint(x);
    return (u16)((u + 0x7FFFu + ((u >> 16) & 1u)) >> 16);
}
__device__ __forceinline__ float bf2f(u16 h) {
    return __uint_as_float(((u32)h) << 16);
}

// ---- K0: split W into bf16 hi/lo, MFMA-fragment-ordered image.
// For e,k: c=k>>5, s=(k>>4)&1, kh=(k>>3)&1, wv=e>>6, nf=(e>>5)&1, em=e&31
// dst_u16 = (c*2+s)*4096 + wv*1024 + nf*512 + kh*256 + em*8 + (k&7)
__global__ __launch_bounds__(256) void wsplit_kernel(
    const float* __restrict__ wgt, u16* __restrict__ Whi, u16* __restrict__ Wlo)
{
    const int idx = blockIdx.x * 256 + threadIdx.x;   // e*256 + ko
    const int e  = idx >> 8;
    const int ko = idx & 255;                          // k-octet
    const int k  = ko * 8;
    const int c  = k >> 5, s = (k >> 4) & 1, kh = (k >> 3) & 1;
    const int dst = (c * 2 + s) * 4096 + (e >> 6) * 1024 + ((e >> 5) & 1) * 512
                  + kh * 256 + (e & 31) * 8;
    const float* p = wgt + (size_t)e * KD + k;
    u16 hi[8], lo[8];
#pragma unroll
    for (int i = 0; i < 8; ++i) {
        const float w = p[i];
        hi[i] = f2bf(w);
        lo[i] = f2bf(w - bf2f(hi[i]));
    }
    *(uint4*)(Whi + dst) = *(const uint4*)hi;
    *(uint4*)(Wlo + dst) = *(const uint4*)lo;
}

// ---- K1: MFMA split-GEMM + top-k + flags + softmax partials ----
__global__ __launch_bounds__(256, 4) void gate_kernel(
    const float* __restrict__ hid, const u16* __restrict__ Whi, const u16* __restrict__ Wlo,
    float* __restrict__ out, float* __restrict__ cnt, float* __restrict__ prb,
    int* __restrict__ flagcnt, int* __restrict__ flaglist)
{
    __shared__ union {
        struct { u16 ah[2][BM][40]; u16 al[2][BM][40]; } st;
        float ls[BM][257];
    } sh;
    __shared__ float maxS[BM], sumS[BM], invS[BM];

    const int tid  = threadIdx.x;
    const int lane = tid & 63;
    const int wv   = tid >> 6;
    const int ln31 = lane & 31;
    const int kh8  = (lane >> 5) * 8;
    const int t0   = blockIdx.x * BM;

    f32x16 acc[2];
#pragma unroll
    for (int nf = 0; nf < 2; ++nf)
#pragma unroll
        for (int r = 0; r < 16; ++r) acc[nf][r] = 0.f;

    // A staging: thread -> (token, k-quad)
    float4 areg;
    const int am = tid >> 3;           // token 0..31
    const int ak = (tid & 7) * 4;      // k 0..28

    auto loadA = [&](int c) {
        areg = *(const float4*)(hid + (size_t)(t0 + am) * KD + c * 32 + ak);
    };
    auto writeA = [&](int buf) {
        float f[4] = {areg.x, areg.y, areg.z, areg.w};
#pragma unroll
        for (int i = 0; i < 4; ++i) {
            const u16 hi = f2bf(f[i]);
            sh.st.ah[buf][am][ak + i] = hi;
            sh.st.al[buf][am][ak + i] = f2bf(f[i] - bf2f(hi));
        }
    };

    loadA(0); writeA(0);
    int cur = 0;

#pragma unroll 1
    for (int c = 0; c < NSTEP; ++c) {
        __syncthreads();                    // As[cur] visible; As[nxt] free
        const int nxt = cur ^ 1;
        if (c + 1 < NSTEP) loadA(c + 1);

        const u16* bbase = (const u16*)0;
#pragma unroll
        for (int s = 0; s < 2; ++s) {
            const int boff = (c * 2 + s) * 4096 + wv * 1024 + lane * 8;
            const bf16x8 bh0 = *(const bf16x8*)(Whi + boff);
            const bf16x8 bl0 = *(const bf16x8*)(Wlo + boff);
            const bf16x8 bh1 = *(const bf16x8*)(Whi + boff + 512);
            const bf16x8 bl1 = *(const bf16x8*)(Wlo + boff + 512);
            const bf16x8 ah  = *(const bf16x8*)&sh.st.ah[cur][ln31][s * 16 + kh8];
            const bf16x8 al  = *(const bf16x8*)&sh.st.al[cur][ln31][s * 16 + kh8];

            acc[0] = __builtin_amdgcn_mfma_f32_32x32x16_bf16(ah, bh0, acc[0], 0, 0, 0);
            acc[0] = __builtin_amdgcn_mfma_f32_32x32x16_bf16(ah, bl0, acc[0], 0, 0, 0);
            acc[0] = __builtin_amdgcn_mfma_f32_32x32x16_bf16(al, bh0, acc[0], 0, 0, 0);
            acc[1] = __builtin_amdgcn_mfma_f32_32x32x16_bf16(ah, bh1, acc[1], 0, 0, 0);
            acc[1] = __builtin_amdgcn_mfma_f32_32x32x16_bf16(ah, bl1, acc[1], 0, 0, 0);
            acc[1] = __builtin_amdgcn_mfma_f32_32x32x16_bf16(al, bh1, acc[1], 0, 0, 0);
        }
        (void)bbase;
        if (c + 1 < NSTEP) writeA(nxt);
        cur = nxt;
    }

    // ---- dump logits (C/D: col=lane&31, row=(r&3)+8*(r>>2)+4*(lane>>5)) ----
    __syncthreads();
#pragma unroll
    for (int nf = 0; nf < 2; ++nf) {
        const int col = wv * 64 + nf * 32 + ln31;
#pragma unroll
        for (int r = 0; r < 16; ++r) {
            const int row = (r & 3) + 8 * (r >> 2) + 4 * (lane >> 5);
            sh.ls[row][col] = acc[nf][r];
        }
    }
    if (tid < BM) sumS[tid] = 0.f;
    __syncthreads();

    // ---- per-token top-k + margin flags (threads 0..31) ----
    if (tid < BM) {
        const float* lr = &sh.ls[tid][0];
        float tv[9]; int ti[9];
#pragma unroll
        for (int j = 0; j < 9; ++j) { tv[j] = -1e30f; ti[j] = 0; }
        float gv3[8], gv4[8];
        float rowmax = -1e30f;

        auto ins9 = [&](float v, int idx) {
#pragma unroll
            for (int p = 0; p < 9; ++p) {
                if (v > tv[p]) {
#pragma unroll
                    for (int q = 8; q > p; --q) { tv[q] = tv[q - 1]; ti[q] = ti[q - 1]; }
                    tv[p] = v; ti[p] = idx;
                    break;
                }
            }
        };

#pragma unroll 1
        for (int g = 0; g < 8; ++g) {
            float v0 = -1e30f, v1 = -1e30f, v2 = -1e30f, v3 = -1e30f, v4 = -1e30f;
            int   i0 = 0, i1 = 0, i2 = 0, i3 = 0;
            for (int j = 0; j < 32; ++j) {
                const float v = lr[g * 32 + j];
                if (v > v0)      { v4=v3; v3=v2;i3=i2; v2=v1;i2=i1; v1=v0;i1=i0; v0=v;i0=j; }
                else if (v > v1) { v4=v3; v3=v2;i3=i2; v2=v1;i2=i1; v1=v;i1=j; }
                else if (v > v2) { v4=v3; v3=v2;i3=i2; v2=v;i2=j; }
                else if (v > v3) { v4=v3; v3=v;i3=j; }
                else if (v > v4) { v4=v; }
            }
            rowmax = fmaxf(rowmax, v0);
            gv3[g] = v3; gv4[g] = v4;
            ins9(v0, g * 32 + i0);
            ins9(v1, g * 32 + i1);
            ins9(v2, g * 32 + i2);
            ins9(v3, g * 32 + i3);
        }

        bool flag = false;
#pragma unroll
        for (int r = 0; r < 8; ++r)
            if (tv[r] - tv[r + 1] < EPS) flag = true;
#pragma unroll
        for (int g = 0; g < 8; ++g)
            if (gv3[g] - gv4[g] < EPS && gv3[g] > tv[7] - EPS) flag = true;

        const float s01 = __fadd_rn(tv[0], tv[1]);
        const float s23 = __fadd_rn(tv[2], tv[3]);
        const float s45 = __fadd_rn(tv[4], tv[5]);
        const float s67 = __fadd_rn(tv[6], tv[7]);
        float s = __fadd_rn(__fadd_rn(s01, s23), __fadd_rn(s45, s67));
        s = __fadd_rn(s, 1e-20f);

        const size_t tg2 = (size_t)(t0 + tid);
#pragma unroll
        for (int j = 0; j < 8; ++j) {
            out[tg2 * 8 + j]                    = (float)ti[j];
            out[(size_t)NTOK * 8 + tg2 * 8 + j] = __fdiv_rn(tv[j], s);
            atomicAdd(&cnt[ti[j]], 1.0f);
        }
        if (flag) {
            const int fi = atomicAdd(flagcnt, 1);
            flaglist[fi] = t0 + tid;
        }
        maxS[tid] = rowmax;
    }
    __syncthreads();

    // ---- softmax denominator (8 threads per token) ----
    {
        const int t  = tid >> 3;
        const int c0 = (tid & 7) * 32;
        const float m = maxS[t];
        float part = 0.f;
#pragma unroll
        for (int j = 0; j < 32; ++j) part += __expf(sh.ls[t][c0 + j] - m);
        atomicAdd(&sumS[t], part);
    }
    __syncthreads();
    if (tid < BM) invS[tid] = 1.0f / sumS[tid];
    __syncthreads();

    // ---- per-expert softmax-prob partial over block tokens ----
    {
        float p = 0.f;
#pragma unroll
        for (int n = 0; n < BM; ++n) p += __expf(sh.ls[n][tid] - maxS[n]) * invS[n];
        atomicAdd(&prb[tid], p);
    }
}

// ---- K2: bit-exact numpy-DAG recompute of flagged tokens (grid-stride) ----
__global__ __launch_bounds__(256) void exact_kernel(
    const float* __restrict__ hid, const float* __restrict__ wgt,
    float* __restrict__ out, float* __restrict__ cnt,
    const int* __restrict__ flagcnt, const int* __restrict__ flaglist)
{
    const int fn = *flagcnt;

    __shared__ float wch[256 * 17];
    __shared__ float hch[8 * 17];
    __shared__ float exls[8][257];
    __shared__ int tk[8];

    const int tid = threadIdx.x;
    const int tg  = tid >> 7;            // 0..1 (4 tokens each)
    const int eg  = (tid >> 2) & 31;     // 0..31
    const int l   = tid & 3;

#pragma unroll 1
    for (int base = blockIdx.x * 8; base < fn; base += 64 * 8) {
        const int nt = min(8, fn - base);
        __syncthreads();
        if (tid < 8) tk[tid] = (tid < nt) ? flaglist[base + tid] : flaglist[base];
        __syncthreads();

        float accq[4][8];
#pragma unroll
        for (int i = 0; i < 4; ++i)
#pragma unroll
            for (int j = 0; j < 8; ++j) accq[i][j] = 0.f;

#pragma unroll 1
        for (int c = 0; c < 128; ++c) {      // 16-blocks ascending
            __syncthreads();
            {
                const float* p = wgt + (size_t)tid * KD + c * 16;
                float4 w0 = *(const float4*)(p);
                float4 w1 = *(const float4*)(p + 4);
                float4 w2 = *(const float4*)(p + 8);
                float4 w3 = *(const float4*)(p + 12);
                float* wr = &wch[tid * 17];
                wr[0]=w0.x; wr[1]=w0.y; wr[2]=w0.z; wr[3]=w0.w;
                wr[4]=w1.x; wr[5]=w1.y; wr[6]=w1.z; wr[7]=w1.w;
                wr[8]=w2.x; wr[9]=w2.y; wr[10]=w2.z; wr[11]=w2.w;
                wr[12]=w3.x; wr[13]=w3.y; wr[14]=w3.z; wr[15]=w3.w;
            }
            if (tid < 128) {
                const int tok = tid >> 4, k = tid & 15;
                hch[tok * 17 + k] = hid[(size_t)tk[tok] * KD + c * 16 + k];
            }
            __syncthreads();

#pragma unroll
            for (int q = 3; q >= 0; --q) {
                const int k = 4 * q + l;
                float hv[4], wv2[8];
#pragma unroll
                for (int i = 0; i < 4; ++i) hv[i] = hch[(tg * 4 + i) * 17 + k];
#pragma unroll
                for (int j = 0; j < 8; ++j) wv2[j] = wch[(j * 32 + eg) * 17 + k];
#pragma unroll
                for (int i = 0; i < 4; ++i)
#pragma unroll
                    for (int j = 0; j < 8; ++j)
                        accq[i][j] = __fadd_rn(__fmul_rn(hv[i], wv2[j]), accq[i][j]);
            }
        }

        __syncthreads();
#pragma unroll
        for (int i = 0; i < 4; ++i)
#pragma unroll
            for (int j = 0; j < 8; ++j) {
                float v = accq[i][j];
                v = __fadd_rn(v, __shfl_xor(v, 1));
                v = __fadd_rn(v, __shfl_xor(v, 2));
                if (l == 0) exls[tg * 4 + i][j * 32 + eg] = v;
            }
        __syncthreads();

        if (tid < nt) {
            const float* lr = &exls[tid][0];
            float tv[8]; int ti[8];
#pragma unroll
            for (int j = 0; j < 8; ++j) { tv[j] = -1e30f; ti[j] = 0; }

            auto ins8 = [&](float v, int idx) {
#pragma unroll
                for (int p = 0; p < 8; ++p) {
                    if (v > tv[p]) {
#pragma unroll
                        for (int q = 7; q > p; --q) { tv[q] = tv[q - 1]; ti[q] = ti[q - 1]; }
                        tv[p] = v; ti[p] = idx;
                        break;
                    }
                }
            };

#pragma unroll 1
            for (int g = 0; g < 8; ++g) {
                float v0 = -1e30f, v1 = -1e30f, v2 = -1e30f, v3 = -1e30f;
                int   i0 = 0, i1 = 0, i2 = 0, i3 = 0;
                for (int j = 0; j < 32; ++j) {
                    const float v = lr[g * 32 + j];
                    if (v > v0)      { v3=v2;i3=i2; v2=v1;i2=i1; v1=v0;i1=i0; v0=v;i0=j; }
                    else if (v > v1) { v3=v2;i3=i2; v2=v1;i2=i1; v1=v;i1=j; }
                    else if (v > v2) { v3=v2;i3=i2; v2=v;i2=j; }
                    else if (v > v3) { v3=v;i3=j; }
                }
                ins8(v0, g * 32 + i0);
                ins8(v1, g * 32 + i1);
                ins8(v2, g * 32 + i2);
                ins8(v3, g * 32 + i3);
            }

            const float s01 = __fadd_rn(tv[0], tv[1]);
            const float s23 = __fadd_rn(tv[2], tv[3]);
            const float s45 = __fadd_rn(tv[4], tv[5]);
            const float s67 = __fadd_rn(tv[6], tv[7]);
            float s = __fadd_rn(__fadd_rn(s01, s23), __fadd_rn(s45, s67));
            s = __fadd_rn(s, 1e-20f);

            const size_t gt = (size_t)tk[tid];
#pragma unroll
            for (int j = 0; j < 8; ++j) {
                const int oldi = (int)out[gt * 8 + j];
                if (oldi != ti[j]) {
                    atomicAdd(&cnt[oldi], -1.0f);
                    atomicAdd(&cnt[ti[j]], 1.0f);
                }
                out[gt * 8 + j]                    = (float)ti[j];
                out[(size_t)NTOK * 8 + gt * 8 + j] = __fdiv_rn(tv[j], s);
            }
        }
        __syncthreads();
    }
}

__global__ void aux_kernel(const float* __restrict__ cnt,
                           const float* __restrict__ prb,
                           float* __restrict__ out)
{
    const int tid = threadIdx.x;
    float v = cnt[tid] * prb[tid];
#pragma unroll
    for (int off = 32; off; off >>= 1) v += __shfl_down(v, off, 64);
    __shared__ float ps[4];
    if ((tid & 63) == 0) ps[tid >> 6] = v;
    __syncthreads();
    if (tid == 0) {
        const float tot = ps[0] + ps[1] + ps[2] + ps[3];
        out[(size_t)NTOK * 8 * 2] = tot * (0.001f / (131072.0f * 16384.0f));
    }
}

extern "C" void kernel_launch(void* const* d_in, const int* in_sizes, int n_in,
                              void* d_out, int out_size, void* d_ws, size_t ws_size,
                              hipStream_t stream)
{
    (void)in_sizes; (void)n_in; (void)out_size; (void)ws_size;
    const float* hid = (const float*)d_in[0];
    const float* wgt = (const float*)d_in[1];
    float* out = (float*)d_out;

    float* cnt      = (float*)d_ws;                  // 256 f
    float* prb      = cnt + NE;                      // 256 f
    int*   flagcnt  = (int*)(prb + NE);              // 1 i (+63 pad)
    int*   flaglist = flagcnt + 64;                  // 16384 i
    u16*   Whi      = (u16*)(flaglist + NTOK);       // 1 MB
    u16*   Wlo      = Whi + (size_t)NE * KD;         // 1 MB

    hipMemsetAsync(d_ws, 0, (2 * NE + 64) * sizeof(float), stream);
    wsplit_kernel<<<NE * KD / 8 / 256, 256, 0, stream>>>(wgt, Whi, Wlo);
    gate_kernel<<<NTOK / BM, 256, 0, stream>>>(hid, Whi, Wlo, out, cnt, prb, flagcnt, flaglist);
    exact_kernel<<<64, 256, 0, stream>>>(hid, wgt, out, cnt, flagcnt, flaglist);
    aux_kernel<<<1, 256, 0, stream>>>(cnt, prb, out);
}

// Round 16
// 486.480 us; speedup vs baseline: 4.9308x; 1.0139x over previous
//
#include <hip/hip_runtime.h>
#include <math.h>

#define NTOK 16384
#define KD   2048
#define NE   256
#define BM   32
#define NSTEP 64              // K-steps of 32
#define EPS  2.5e-4f

using bf16x8 = __attribute__((ext_vector_type(8))) short;
using f32x16 = __attribute__((ext_vector_type(16))) float;
using u16 = unsigned short;
using u32 = unsigned int;

__device__ __forceinline__ u16 f2bf(float x) {
    u32 u = __float_as_uint(x);
    return (u16)((u + 0x7FFFu + ((u >> 16) & 1u)) >> 16);
}
__device__ __forceinline__ float bf2f(u16 h) {
    return __uint_as_float(((u32)h) << 16);
}

// ---- K0: split W into bf16 hi/lo, MFMA-fragment-ordered image.
// dst_u16 = (c*2+s)*4096 + wv*1024 + nf*512 + kh*256 + em*8 + (k&7)
__global__ __launch_bounds__(256) void wsplit_kernel(
    const float* __restrict__ wgt, u16* __restrict__ Whi, u16* __restrict__ Wlo)
{
    const int idx = blockIdx.x * 256 + threadIdx.x;   // e*256 + ko
    const int e  = idx >> 8;
    const int ko = idx & 255;                          // k-octet
    const int k  = ko * 8;
    const int c  = k >> 5, s = (k >> 4) & 1, kh = (k >> 3) & 1;
    const int dst = (c * 2 + s) * 4096 + (e >> 6) * 1024 + ((e >> 5) & 1) * 512
                  + kh * 256 + (e & 31) * 8;
    const float* p = wgt + (size_t)e * KD + k;
    u16 hi[8], lo[8];
#pragma unroll
    for (int i = 0; i < 8; ++i) {
        const float w = p[i];
        hi[i] = f2bf(w);
        lo[i] = f2bf(w - bf2f(hi[i]));
    }
    *(uint4*)(Whi + dst) = *(const uint4*)hi;
    *(uint4*)(Wlo + dst) = *(const uint4*)lo;
}

#define MFMA32(A, B, C) __builtin_amdgcn_mfma_f32_32x32x16_bf16((A), (B), (C), 0, 0, 0)

// ---- K1: MFMA split-GEMM, B register-double-buffered ----
__global__ __launch_bounds__(256) void gate_kernel(
    const float* __restrict__ hid, const u16* __restrict__ Whi, const u16* __restrict__ Wlo,
    float* __restrict__ out, float* __restrict__ cnt, float* __restrict__ prb,
    int* __restrict__ flagcnt, int* __restrict__ flaglist)
{
    __shared__ union {
        struct { u16 ah[2][BM][40]; u16 al[2][BM][40]; } st;
        float ls[BM][257];
    } sh;
    __shared__ float maxS[BM], sumS[BM], invS[BM];

    const int tid  = threadIdx.x;
    const int lane = tid & 63;
    const int wv   = tid >> 6;
    const int ln31 = lane & 31;
    const int kh8  = (lane >> 5) * 8;
    const int t0   = blockIdx.x * BM;

    f32x16 acc[2];
#pragma unroll
    for (int nf = 0; nf < 2; ++nf)
#pragma unroll
        for (int r = 0; r < 16; ++r) acc[nf][r] = 0.f;

    // A staging: thread -> (token, k-quad)
    float4 areg;
    const int am = tid >> 3;           // token 0..31
    const int ak = (tid & 7) * 4;      // k 0..28

    auto loadA = [&](int c) {
        areg = *(const float4*)(hid + (size_t)(t0 + am) * KD + c * 32 + ak);
    };
    auto writeA = [&](int buf) {
        float f[4] = {areg.x, areg.y, areg.z, areg.w};
#pragma unroll
        for (int i = 0; i < 4; ++i) {
            const u16 hi = f2bf(f[i]);
            sh.st.ah[buf][am][ak + i] = hi;
            sh.st.al[buf][am][ak + i] = f2bf(f[i] - bf2f(hi));
        }
    };

    const u16* bwh = Whi + wv * 1024 + lane * 8;
    const u16* bwl = Wlo + wv * 1024 + lane * 8;

    bf16x8 p0h0, p0l0, p0h1, p0l1, p0h2, p0l2, p0h3, p0l3;
    bf16x8 p1h0, p1l0, p1h1, p1l1, p1h2, p1l2, p1h3, p1l3;

#define LOADB(P, cc) do {                                           \
    const u16* _ph = bwh + (cc) * 8192;                             \
    const u16* _pl = bwl + (cc) * 8192;                             \
    P##h0 = *(const bf16x8*)(_ph);                                  \
    P##l0 = *(const bf16x8*)(_pl);                                  \
    P##h1 = *(const bf16x8*)(_ph + 512);                            \
    P##l1 = *(const bf16x8*)(_pl + 512);                            \
    P##h2 = *(const bf16x8*)(_ph + 4096);                           \
    P##l2 = *(const bf16x8*)(_pl + 4096);                           \
    P##h3 = *(const bf16x8*)(_ph + 4608);                           \
    P##l3 = *(const bf16x8*)(_pl + 4608);                           \
} while (0)

#define COMPUTE(P, CUR) do {                                        \
    bf16x8 ah0 = *(const bf16x8*)&sh.st.ah[CUR][ln31][kh8];         \
    bf16x8 al0 = *(const bf16x8*)&sh.st.al[CUR][ln31][kh8];         \
    acc[0] = MFMA32(ah0, P##h0, acc[0]);                            \
    acc[0] = MFMA32(ah0, P##l0, acc[0]);                            \
    acc[0] = MFMA32(al0, P##h0, acc[0]);                            \
    acc[1] = MFMA32(ah0, P##h1, acc[1]);                            \
    acc[1] = MFMA32(ah0, P##l1, acc[1]);                            \
    acc[1] = MFMA32(al0, P##h1, acc[1]);                            \
    bf16x8 ah1 = *(const bf16x8*)&sh.st.ah[CUR][ln31][16 + kh8];    \
    bf16x8 al1 = *(const bf16x8*)&sh.st.al[CUR][ln31][16 + kh8];    \
    acc[0] = MFMA32(ah1, P##h2, acc[0]);                            \
    acc[0] = MFMA32(ah1, P##l2, acc[0]);                            \
    acc[0] = MFMA32(al1, P##h2, acc[0]);                            \
    acc[1] = MFMA32(ah1, P##h3, acc[1]);                            \
    acc[1] = MFMA32(ah1, P##l3, acc[1]);                            \
    acc[1] = MFMA32(al1, P##h3, acc[1]);                            \
} while (0)

    // prologue
    loadA(0);
    writeA(0);
    LOADB(p0, 0);
    __syncthreads();

#pragma unroll 1
    for (int c = 0; c < NSTEP; c += 2) {
        // even body: compute p0/As[0], prefetch c+1 into p1/As[1]
        loadA(c + 1);
        LOADB(p1, c + 1);
        COMPUTE(p0, 0);
        writeA(1);
        __syncthreads();
        // odd body: compute p1/As[1], prefetch c+2 into p0/As[0]
        if (c + 2 < NSTEP) {
            loadA(c + 2);
            LOADB(p0, c + 2);
        }
        COMPUTE(p1, 1);
        if (c + 2 < NSTEP) writeA(0);
        __syncthreads();
    }

    // ---- dump logits (C/D: col=lane&31, row=(r&3)+8*(r>>2)+4*(lane>>5)) ----
#pragma unroll
    for (int nf = 0; nf < 2; ++nf) {
        const int col = wv * 64 + nf * 32 + ln31;
#pragma unroll
        for (int r = 0; r < 16; ++r) {
            const int row = (r & 3) + 8 * (r >> 2) + 4 * (lane >> 5);
            sh.ls[row][col] = acc[nf][r];
        }
    }
    if (tid < BM) sumS[tid] = 0.f;
    __syncthreads();

    // ---- per-token top-k + margin flags (threads 0..31) ----
    if (tid < BM) {
        const float* lr = &sh.ls[tid][0];
        float tv[9]; int ti[9];
#pragma unroll
        for (int j = 0; j < 9; ++j) { tv[j] = -1e30f; ti[j] = 0; }
        float gv3[8], gv4[8];
        float rowmax = -1e30f;

        auto ins9 = [&](float v, int idx) {
#pragma unroll
            for (int p = 0; p < 9; ++p) {
                if (v > tv[p]) {
#pragma unroll
                    for (int q = 8; q > p; --q) { tv[q] = tv[q - 1]; ti[q] = ti[q - 1]; }
                    tv[p] = v; ti[p] = idx;
                    break;
                }
            }
        };

#pragma unroll 1
        for (int g = 0; g < 8; ++g) {
            float v0 = -1e30f, v1 = -1e30f, v2 = -1e30f, v3 = -1e30f, v4 = -1e30f;
            int   i0 = 0, i1 = 0, i2 = 0, i3 = 0;
            for (int j = 0; j < 32; ++j) {
                const float v = lr[g * 32 + j];
                if (v > v0)      { v4=v3; v3=v2;i3=i2; v2=v1;i2=i1; v1=v0;i1=i0; v0=v;i0=j; }
                else if (v > v1) { v4=v3; v3=v2;i3=i2; v2=v1;i2=i1; v1=v;i1=j; }
                else if (v > v2) { v4=v3; v3=v2;i3=i2; v2=v;i2=j; }
                else if (v > v3) { v4=v3; v3=v;i3=j; }
                else if (v > v4) { v4=v; }
            }
            rowmax = fmaxf(rowmax, v0);
            gv3[g] = v3; gv4[g] = v4;
            ins9(v0, g * 32 + i0);
            ins9(v1, g * 32 + i1);
            ins9(v2, g * 32 + i2);
            ins9(v3, g * 32 + i3);
        }

        bool flag = false;
#pragma unroll
        for (int r = 0; r < 8; ++r)
            if (tv[r] - tv[r + 1] < EPS) flag = true;
#pragma unroll
        for (int g = 0; g < 8; ++g)
            if (gv3[g] - gv4[g] < EPS && gv3[g] > tv[7] - EPS) flag = true;

        const float s01 = __fadd_rn(tv[0], tv[1]);
        const float s23 = __fadd_rn(tv[2], tv[3]);
        const float s45 = __fadd_rn(tv[4], tv[5]);
        const float s67 = __fadd_rn(tv[6], tv[7]);
        float s = __fadd_rn(__fadd_rn(s01, s23), __fadd_rn(s45, s67));
        s = __fadd_rn(s, 1e-20f);

        const size_t tg2 = (size_t)(t0 + tid);
#pragma unroll
        for (int j = 0; j < 8; ++j) {
            out[tg2 * 8 + j]                    = (float)ti[j];
            out[(size_t)NTOK * 8 + tg2 * 8 + j] = __fdiv_rn(tv[j], s);
            atomicAdd(&cnt[ti[j]], 1.0f);
        }
        if (flag) {
            const int fi = atomicAdd(flagcnt, 1);
            flaglist[fi] = t0 + tid;
        }
        maxS[tid] = rowmax;
    }
    __syncthreads();

    // ---- softmax denominator (8 threads per token) ----
    {
        const int t  = tid >> 3;
        const int c0 = (tid & 7) * 32;
        const float m = maxS[t];
        float part = 0.f;
#pragma unroll
        for (int j = 0; j < 32; ++j) part += __expf(sh.ls[t][c0 + j] - m);
        atomicAdd(&sumS[t], part);
    }
    __syncthreads();
    if (tid < BM) invS[tid] = 1.0f / sumS[tid];
    __syncthreads();

    // ---- per-expert softmax-prob partial over block tokens ----
    {
        float p = 0.f;
#pragma unroll
        for (int n = 0; n < BM; ++n) p += __expf(sh.ls[n][tid] - maxS[n]) * invS[n];
        atomicAdd(&prb[tid], p);
    }
}

// ---- K2: bit-exact numpy-DAG recompute of flagged tokens (grid-stride) ----
__global__ __launch_bounds__(256) void exact_kernel(
    const float* __restrict__ hid, const float* __restrict__ wgt,
    float* __restrict__ out, float* __restrict__ cnt,
    const int* __restrict__ flagcnt, const int* __restrict__ flaglist)
{
    const int fn = *flagcnt;

    __shared__ float wch[256 * 17];
    __shared__ float hch[8 * 17];
    __shared__ float exls[8][257];
    __shared__ int tk[8];

    const int tid = threadIdx.x;
    const int tg  = tid >> 7;            // 0..1 (4 tokens each)
    const int eg  = (tid >> 2) & 31;     // 0..31
    const int l   = tid & 3;

#pragma unroll 1
    for (int base = blockIdx.x * 8; base < fn; base += gridDim.x * 8) {
        const int nt = min(8, fn - base);
        __syncthreads();
        if (tid < 8) tk[tid] = (tid < nt) ? flaglist[base + tid] : flaglist[base];
        __syncthreads();

        float accq[4][8];
#pragma unroll
        for (int i = 0; i < 4; ++i)
#pragma unroll
            for (int j = 0; j < 8; ++j) accq[i][j] = 0.f;

#pragma unroll 1
        for (int c = 0; c < 128; ++c) {      // 16-blocks ascending
            __syncthreads();
            {
                const float* p = wgt + (size_t)tid * KD + c * 16;
                float4 w0 = *(const float4*)(p);
                float4 w1 = *(const float4*)(p + 4);
                float4 w2 = *(const float4*)(p + 8);
                float4 w3 = *(const float4*)(p + 12);
                float* wr = &wch[tid * 17];
                wr[0]=w0.x; wr[1]=w0.y; wr[2]=w0.z; wr[3]=w0.w;
                wr[4]=w1.x; wr[5]=w1.y; wr[6]=w1.z; wr[7]=w1.w;
                wr[8]=w2.x; wr[9]=w2.y; wr[10]=w2.z; wr[11]=w2.w;
                wr[12]=w3.x; wr[13]=w3.y; wr[14]=w3.z; wr[15]=w3.w;
            }
            if (tid < 128) {
                const int tok = tid >> 4, k = tid & 15;
                hch[tok * 17 + k] = hid[(size_t)tk[tok] * KD + c * 16 + k];
            }
            __syncthreads();

#pragma unroll
            for (int q = 3; q >= 0; --q) {
                const int k = 4 * q + l;
                float hv[4], wv2[8];
#pragma unroll
                for (int i = 0; i < 4; ++i) hv[i] = hch[(tg * 4 + i) * 17 + k];
#pragma unroll
                for (int j = 0; j < 8; ++j) wv2[j] = wch[(j * 32 + eg) * 17 + k];
#pragma unroll
                for (int i = 0; i < 4; ++i)
#pragma unroll
                    for (int j = 0; j < 8; ++j)
                        accq[i][j] = __fadd_rn(__fmul_rn(hv[i], wv2[j]), accq[i][j]);
            }
        }

        __syncthreads();
#pragma unroll
        for (int i = 0; i < 4; ++i)
#pragma unroll
            for (int j = 0; j < 8; ++j) {
                float v = accq[i][j];
                v = __fadd_rn(v, __shfl_xor(v, 1));
                v = __fadd_rn(v, __shfl_xor(v, 2));
                if (l == 0) exls[tg * 4 + i][j * 32 + eg] = v;
            }
        __syncthreads();

        if (tid < nt) {
            const float* lr = &exls[tid][0];
            float tv[8]; int ti[8];
#pragma unroll
            for (int j = 0; j < 8; ++j) { tv[j] = -1e30f; ti[j] = 0; }

            auto ins8 = [&](float v, int idx) {
#pragma unroll
                for (int p = 0; p < 8; ++p) {
                    if (v > tv[p]) {
#pragma unroll
                        for (int q = 7; q > p; --q) { tv[q] = tv[q - 1]; ti[q] = ti[q - 1]; }
                        tv[p] = v; ti[p] = idx;
                        break;
                    }
                }
            };

#pragma unroll 1
            for (int g = 0; g < 8; ++g) {
                float v0 = -1e30f, v1 = -1e30f, v2 = -1e30f, v3 = -1e30f;
                int   i0 = 0, i1 = 0, i2 = 0, i3 = 0;
                for (int j = 0; j < 32; ++j) {
                    const float v = lr[g * 32 + j];
                    if (v > v0)      { v3=v2;i3=i2; v2=v1;i2=i1; v1=v0;i1=i0; v0=v;i0=j; }
                    else if (v > v1) { v3=v2;i3=i2; v2=v1;i2=i1; v1=v;i1=j; }
                    else if (v > v2) { v3=v2;i3=i2; v2=v;i2=j; }
                    else if (v > v3) { v3=v;i3=j; }
                }
                ins8(v0, g * 32 + i0);
                ins8(v1, g * 32 + i1);
                ins8(v2, g * 32 + i2);
                ins8(v3, g * 32 + i3);
            }

            const float s01 = __fadd_rn(tv[0], tv[1]);
            const float s23 = __fadd_rn(tv[2], tv[3]);
            const float s45 = __fadd_rn(tv[4], tv[5]);
            const float s67 = __fadd_rn(tv[6], tv[7]);
            float s = __fadd_rn(__fadd_rn(s01, s23), __fadd_rn(s45, s67));
            s = __fadd_rn(s, 1e-20f);

            const size_t gt = (size_t)tk[tid];
#pragma unroll
            for (int j = 0; j < 8; ++j) {
                const int oldi = (int)out[gt * 8 + j];
                if (oldi != ti[j]) {
                    atomicAdd(&cnt[oldi], -1.0f);
                    atomicAdd(&cnt[ti[j]], 1.0f);
                }
                out[gt * 8 + j]                    = (float)ti[j];
                out[(size_t)NTOK * 8 + gt * 8 + j] = __fdiv_rn(tv[j], s);
            }
        }
        __syncthreads();
    }
}

__global__ void aux_kernel(const float* __restrict__ cnt,
                           const float* __restrict__ prb,
                           float* __restrict__ out)
{
    const int tid = threadIdx.x;
    float v = cnt[tid] * prb[tid];
#pragma unroll
    for (int off = 32; off; off >>= 1) v += __shfl_down(v, off, 64);
    __shared__ float ps[4];
    if ((tid & 63) == 0) ps[tid >> 6] = v;
    __syncthreads();
    if (tid == 0) {
        const float tot = ps[0] + ps[1] + ps[2] + ps[3];
        out[(size_t)NTOK * 8 * 2] = tot * (0.001f / (131072.0f * 16384.0f));
    }
}

extern "C" void kernel_launch(void* const* d_in, const int* in_sizes, int n_in,
                              void* d_out, int out_size, void* d_ws, size_t ws_size,
                              hipStream_t stream)
{
    (void)in_sizes; (void)n_in; (void)out_size; (void)ws_size;
    const float* hid = (const float*)d_in[0];
    const float* wgt = (const float*)d_in[1];
    float* out = (float*)d_out;

    float* cnt      = (float*)d_ws;                  // 256 f
    float* prb      = cnt + NE;                      // 256 f
    int*   flagcnt  = (int*)(prb + NE);              // 1 i (+63 pad)
    int*   flaglist = flagcnt + 64;                  // 16384 i
    u16*   Whi      = (u16*)(flaglist + NTOK);       // 1 MB
    u16*   Wlo      = Whi + (size_t)NE * KD;         // 1 MB

    hipMemsetAsync(d_ws, 0, (2 * NE + 64) * sizeof(float), stream);
    wsplit_kernel<<<NE * KD / 8 / 256, 256, 0, stream>>>(wgt, Whi, Wlo);
    gate_kernel<<<NTOK / BM, 256, 0, stream>>>(hid, Whi, Wlo, out, cnt, prb, flagcnt, flaglist);
    exact_kernel<<<64, 256, 0, stream>>>(hid, wgt, out, cnt, flagcnt, flaglist);
    aux_kernel<<<1, 256, 0, stream>>>(cnt, prb, out);
}